// Round 2
// baseline (486.269 us; speedup 1.0000x reference)
//
#include <hip/hip_runtime.h>
#include <hip/hip_bf16.h>

typedef unsigned short u16;
typedef unsigned char  u8;
typedef unsigned int   u32;
typedef __attribute__((ext_vector_type(8))) short short8;
typedef __attribute__((ext_vector_type(4))) float floatx4;
typedef __attribute__((ext_vector_type(2))) float floatx2;

__device__ __forceinline__ float bits2f(u32 v){ float f; __builtin_memcpy(&f, &v, 4); return f; }
__device__ __forceinline__ u16 f2bf(float f){
    __hip_bfloat16 h = __float2bfloat16(f);
    u16 u; __builtin_memcpy(&u, &h, 2); return u;
}

// ---------------- f32 -> bf16 + fp8 conversion (x into hbuf, x8) ----------------

__global__ __launch_bounds__(256) void cvt_kernel(const float* __restrict__ in,
                                                  u16* __restrict__ out,
                                                  u32* __restrict__ out8, int total4){
    int i = blockIdx.x * 256 + threadIdx.x;   // 4 floats per thread
    if (i >= total4) return;
    float4 v = ((const float4*)in)[i];
    uint2 o;
    o.x = (u32)f2bf(v.x) | ((u32)f2bf(v.y) << 16);
    o.y = (u32)f2bf(v.z) | ((u32)f2bf(v.w) << 16);
    ((uint2*)out)[i] = o;
    u32 p8 = (u32)__builtin_amdgcn_cvt_pk_fp8_f32(v.x, v.y, 0, false);
    p8     = (u32)__builtin_amdgcn_cvt_pk_fp8_f32(v.z, v.w, (int)p8, true);
    out8[i] = p8;
}

// ------- bf16 pre -> fp8 activated table: fp8(relu(pre*sc + sh)) (dense affine, not per-edge) -------

__global__ __launch_bounds__(256) void cvt8a_kernel(const u16* __restrict__ in,
                                                    const float* __restrict__ cs,
                                                    uint2* __restrict__ out8, int total8){
    int i = blockIdx.x * 256 + threadIdx.x;   // 8 bf16 per thread
    if (i >= total8) return;
    const int c0 = (i & 15) * 8;              // 128 channels per row, 16 threads/row
    uint4 v = ((const uint4*)in)[i];
    u32 w[4] = {v.x, v.y, v.z, v.w};
    float f[8];
    #pragma unroll
    for (int j = 0; j < 4; ++j){
        f[2*j]   = bits2f(w[j] << 16);
        f[2*j+1] = bits2f(w[j] & 0xffff0000u);
    }
    #pragma unroll
    for (int j = 0; j < 8; ++j)
        f[j] = fmaxf(fmaf(f[j], cs[256 + c0 + j], cs[384 + c0 + j]), 0.f);
    u32 lo = (u32)__builtin_amdgcn_cvt_pk_fp8_f32(f[0], f[1], 0, false);
    lo     = (u32)__builtin_amdgcn_cvt_pk_fp8_f32(f[2], f[3], (int)lo, true);
    u32 hi = (u32)__builtin_amdgcn_cvt_pk_fp8_f32(f[4], f[5], 0, false);
    hi     = (u32)__builtin_amdgcn_cvt_pk_fp8_f32(f[6], f[7], (int)hi, true);
    uint2 o; o.x = lo; o.y = hi;
    out8[i] = o;
}

// ---------------- CSR build: bucket hist -> bucket scan -> multisplit bin -> bucket sort ----------------

__global__ __launch_bounds__(256) void bhist_kernel(const int* __restrict__ dst,
                                                    int* __restrict__ gbcnt, int E){
    __shared__ int bc[256];
    const int t = threadIdx.x;
    bc[t] = 0;
    __syncthreads();
    const int tile0 = blockIdx.x * 8192;
    const int cnt = min(8192, E - tile0);
    for (int j = t; j < cnt; j += 256) atomicAdd(&bc[dst[tile0 + j] >> 9], 1);
    __syncthreads();
    if (bc[t] > 0) atomicAdd(&gbcnt[t], bc[t]);
}

__global__ __launch_bounds__(256) void bscan_kernel(const int* __restrict__ gbcnt,
                                                    int* __restrict__ bbase,
                                                    int* __restrict__ bcur, int nbuk){
    __shared__ int ws[4];
    const int t = threadIdx.x, lane = t & 63, wv = t >> 6;
    int v = (t < nbuk) ? gbcnt[t] : 0;
    int s = v;
    for (int off = 1; off < 64; off <<= 1){
        int n = __shfl_up(s, off);
        if (lane >= off) s += n;
    }
    if (lane == 63) ws[wv] = s;
    __syncthreads();
    int woff = 0;
    for (int w = 0; w < wv; ++w) woff += ws[w];
    int excl = s + woff - v;
    if (t < nbuk){ bbase[t] = excl; bcur[t] = excl; }
}

#define BIN_TILE 8192
__global__ __launch_bounds__(256) void bin_kernel(const int* __restrict__ src,
                                                  const int* __restrict__ dst,
                                                  int* __restrict__ bcur,
                                                  u32* __restrict__ pairs, int E, int nbuk){
    __shared__ u32 hcnt[256], hexcl[256], hoff[256];
    __shared__ int gbase[256];
    __shared__ u32 stage[BIN_TILE];
    __shared__ unsigned char bkt[BIN_TILE];
    const int t = threadIdx.x;
    const int tile0 = blockIdx.x * BIN_TILE;
    const int cntE = min(BIN_TILE, E - tile0);

    hcnt[t] = 0;
    __syncthreads();
    for (int j = t; j < cntE; j += 256){
        int d = dst[tile0 + j];
        atomicAdd(&hcnt[d >> 9], 1u);
    }
    __syncthreads();
    if (t < 64){
        u32 a0 = hcnt[4*t], a1 = hcnt[4*t+1], a2 = hcnt[4*t+2], a3 = hcnt[4*t+3];
        u32 lsum = a0 + a1 + a2 + a3;
        u32 s = lsum;
        for (int off = 1; off < 64; off <<= 1){
            u32 n = __shfl_up(s, off);
            if (t >= off) s += n;
        }
        u32 base = s - lsum;
        hexcl[4*t]   = base;
        hexcl[4*t+1] = base + a0;
        hexcl[4*t+2] = base + a0 + a1;
        hexcl[4*t+3] = base + a0 + a1 + a2;
        hoff[4*t]   = base;
        hoff[4*t+1] = base + a0;
        hoff[4*t+2] = base + a0 + a1;
        hoff[4*t+3] = base + a0 + a1 + a2;
    }
    __syncthreads();
    if (t < nbuk && hcnt[t] > 0) gbase[t] = atomicAdd(&bcur[t], (int)hcnt[t]);
    for (int j = t; j < cntE; j += 256){
        int d = dst[tile0 + j];
        int s = src[tile0 + j];
        int b = d >> 9;
        u32 p = atomicAdd(&hoff[b], 1u);
        stage[p] = ((u32)s << 9) | (u32)(d & 511);
        bkt[p] = (unsigned char)b;
    }
    __syncthreads();
    for (int j = t; j < cntE; j += 256){
        int b = bkt[j];
        pairs[gbase[b] + (int)((u32)j - hexcl[b])] = stage[j];
    }
}

__global__ __launch_bounds__(256) void sort2_kernel(const u32* __restrict__ pairs,
                                                    const int* __restrict__ bbase,
                                                    int* __restrict__ indptr,
                                                    float* __restrict__ invdeg,
                                                    int* __restrict__ esrc,
                                                    int M, int E, int nbuk){
    __shared__ int ndeg[512];
    __shared__ int cur[512];
    __shared__ int wsI[4];
    const int b = blockIdx.x;
    const int node0 = b * 512;
    const int lo = bbase[b];
    const int hi = (b + 1 < nbuk) ? bbase[b + 1] : E;
    const int t = threadIdx.x, lane = t & 63, wv = t >> 6;

    ndeg[t] = 0; ndeg[t + 256] = 0;
    __syncthreads();
    for (int i = lo + t; i < hi; i += 256) atomicAdd(&ndeg[pairs[i] & 511], 1);
    __syncthreads();

    const int d0 = ndeg[2*t], d1 = ndeg[2*t + 1];
    const int p = d0 + d1;
    int s = p;
    for (int off = 1; off < 64; off <<= 1){
        int n = __shfl_up(s, off);
        if (lane >= off) s += n;
    }
    if (lane == 63) wsI[wv] = s;
    __syncthreads();
    int woff = 0;
    for (int w = 0; w < wv; ++w) woff += wsI[w];
    const int incl = s + woff;
    const int excl0 = incl - p;
    const int excl1 = excl0 + d0;

    const int n0 = node0 + 2*t, n1 = node0 + 2*t + 1;
    if (n0 < M){
        indptr[n0 + 1] = lo + excl0 + d0;
        invdeg[n0] = 1.0f / (float)max(d0, 1);
        cur[2*t] = lo + excl0;
    }
    if (n1 < M){
        indptr[n1 + 1] = lo + excl1 + d1;
        invdeg[n1] = 1.0f / (float)max(d1, 1);
        cur[2*t + 1] = lo + excl1;
    }
    if (b == 0 && t == 0) indptr[0] = 0;
    __syncthreads();
    for (int i = lo + t; i < hi; i += 256){
        u32 v = pairs[i];
        int pos = atomicAdd(&cur[v & 511], 1);
        esrc[pos] = (int)(v >> 9);
    }
}

// ------- weight packing -------

__global__ void pack_kernel(const float* __restrict__ wself, const float* __restrict__ wneigh,
                            u16* __restrict__ bp, int N){
    int i = blockIdx.x * 256 + threadIdx.x;
    if (i >= N * 256) return;
    int n = i >> 8, k = i & 255;
    float v = (k < 128) ? wself[k * N + n] : wneigh[(k - 128) * N + n];
    bp[i] = f2bf(v);
}

// ---------------- aggregation over fp8 table ----------------
// One 8-lane group per node (8 nodes/wave, 32 nodes/block). Each group walks
// its CSR range serially in 4-edge chunks; lane l8 owns 16 fp8 channels (16 B).

__global__ __launch_bounds__(256) void agg_kernel(const u8* __restrict__ h8,
                                                  const int* __restrict__ indptr,
                                                  const int* __restrict__ esrc,
                                                  const float* __restrict__ invdeg,
                                                  u16* __restrict__ agg, int M){
    const int l8 = threadIdx.x & 7;
    const int n = (blockIdx.x * 256 + threadIdx.x) >> 3;
    if (n >= M) return;
    const int beg = indptr[n];
    const int end = indptr[n + 1];
    const float fs = invdeg[n];

    floatx2 acc[8];
    #pragma unroll
    for (int i = 0; i < 8; ++i){ acc[i].x = 0.f; acc[i].y = 0.f; }

    const u8* hb = h8 + l8 * 16;

    auto accum = [&](uint4 v){
        u32 w[4] = {v.x, v.y, v.z, v.w};
        #pragma unroll
        for (int j = 0; j < 4; ++j){
            acc[2*j]   += __builtin_amdgcn_cvt_pk_f32_fp8(w[j], false);
            acc[2*j+1] += __builtin_amdgcn_cvt_pk_f32_fp8(w[j], true);
        }
    };

    int e = beg;
    for (; e + 4 <= end; e += 4){
        const int i0 = esrc[e];
        const int i1 = esrc[e + 1];
        const int i2 = esrc[e + 2];
        const int i3 = esrc[e + 3];
        uint4 v0 = *(const uint4*)(hb + (size_t)i0 * 128);
        uint4 v1 = *(const uint4*)(hb + (size_t)i1 * 128);
        uint4 v2 = *(const uint4*)(hb + (size_t)i2 * 128);
        uint4 v3 = *(const uint4*)(hb + (size_t)i3 * 128);
        accum(v0); accum(v1); accum(v2); accum(v3);
    }
    for (; e < end; ++e){
        const int i0 = esrc[e];
        uint4 v0 = *(const uint4*)(hb + (size_t)i0 * 128);
        accum(v0);
    }

    u32 o[8];
    #pragma unroll
    for (int k = 0; k < 8; ++k)
        o[k] = (u32)f2bf(acc[k].x * fs) | ((u32)f2bf(acc[k].y * fs) << 16);
    uint4 w0 = {o[0], o[1], o[2], o[3]};
    uint4 w1 = {o[4], o[5], o[6], o[7]};
    *(uint4*)(agg + (size_t)n * 128 + l8 * 16)     = w0;
    *(uint4*)(agg + (size_t)n * 128 + l8 * 16 + 8) = w1;
}

// ------- GEMM: B pinned in registers, A streamed (3-deep rotation), fused bias + BN stats -------
// C-tile epilogue staged through LDS -> fully coalesced dwordx4 stores (no partial-line RFO).

template<int NTW, bool STATS, bool AFFA>
__global__ __launch_bounds__(256, 2) void gemm2_kernel(const u16* __restrict__ hA,
                                                       const u16* __restrict__ aggA,
                                                       const u16* __restrict__ Bp,
                                                       const float* __restrict__ bias,
                                                       const float* __restrict__ cs,
                                                       void* __restrict__ outPre,
                                                       float* __restrict__ partials,
                                                       int M, int T, int nstream){
    constexpr int N = NTW * 32;
    __shared__ float sbuf[4][N], s2buf[4][N];
    __shared__ float s_sc[128], s_sh[128];
    __shared__ u16 cstg[4][16][72];   // per-wave 16 x 64 (u16) or 16 x 32 (f32) tile, stride 144 B
    const int wave = threadIdx.x >> 6;
    const int lane = threadIdx.x & 63;
    const int m15 = lane & 15;
    const int quad = lane >> 4;
    const int colbase = (wave & 1) * (NTW * 16);

    if (STATS){
        for (int i = threadIdx.x; i < 4 * N; i += 256){
            ((float*)sbuf)[i] = 0.f;
            ((float*)s2buf)[i] = 0.f;
        }
    }
    if (AFFA && threadIdx.x < 128){
        s_sc[threadIdx.x] = cs[256 + threadIdx.x];
        s_sh[threadIdx.x] = cs[384 + threadIdx.x];
    }
    if (STATS || AFFA) __syncthreads();

    short8 breg[NTW][8];
    float bv[NTW];
    #pragma unroll
    for (int nt = 0; nt < NTW; ++nt){
        bv[nt] = bias[colbase + nt * 16 + m15];
        #pragma unroll
        for (int k0 = 0; k0 < 8; ++k0)
            breg[nt][k0] = *(const short8*)(Bp + (size_t)(colbase + nt * 16 + m15) * 256 + k0 * 32 + quad * 8);
    }

    float sS[NTW], sQ[NTW];
    #pragma unroll
    for (int nt = 0; nt < NTW; ++nt){ sS[nt] = 0.f; sQ[nt] = 0.f; }

    auto loadA = [&](short8* buf, int tile){
        int arow = tile * 16 + m15;
        if (arow >= M) arow = M - 1;
        const u16* p0 = hA   + (size_t)arow * 128 + quad * 8;
        const u16* p1 = aggA + (size_t)arow * 128 + quad * 8;
        #pragma unroll
        for (int k0 = 0; k0 < 4; ++k0) buf[k0]     = *(const short8*)(p0 + k0 * 32);
        #pragma unroll
        for (int k0 = 0; k0 < 4; ++k0) buf[4 + k0] = *(const short8*)(p1 + k0 * 32);
    };

    auto compute = [&](short8* buf, int tile){
        if (AFFA){
            #pragma unroll
            for (int k0 = 0; k0 < 4; ++k0){
                const int cb = k0 * 32 + quad * 8;
                short8 raw = buf[k0];
                #pragma unroll
                for (int j = 0; j < 8; ++j){
                    float f = bits2f(((u32)(u16)raw[j]) << 16);
                    f = fmaxf(fmaf(f, s_sc[cb + j], s_sh[cb + j]), 0.f);
                    raw[j] = (short)f2bf(f);
                }
                buf[k0] = raw;
            }
        }
        floatx4 acc[NTW];
        #pragma unroll
        for (int nt = 0; nt < NTW; ++nt) acc[nt] = 0.0f;
        #pragma unroll
        for (int k0 = 0; k0 < 8; ++k0)
            #pragma unroll
            for (int nt = 0; nt < NTW; ++nt)
                acc[nt] = __builtin_amdgcn_mfma_f32_16x16x32_bf16(buf[k0], breg[nt][k0], acc[nt], 0, 0, 0);

        // ---- epilogue: stage into LDS, then coalesced wide stores ----
        const int r0 = quad * 4;
        #pragma unroll
        for (int nt = 0; nt < NTW; ++nt){
            #pragma unroll
            for (int r = 0; r < 4; ++r){
                float v = acc[nt][r] + bv[nt];
                if (STATS){
                    int row = tile * 16 + r0 + r;
                    if (row < M){
                        sS[nt] += v;
                        sQ[nt] = fmaf(v, v, sQ[nt]);
                    }
                    cstg[wave][r0 + r][nt * 16 + m15] = f2bf(v);
                } else {
                    ((float*)&cstg[wave][0][0])[(r0 + r) * 36 + nt * 16 + m15] = v;
                }
            }
        }
        asm volatile("s_waitcnt lgkmcnt(0)" ::: "memory");
        const int lrow = lane >> 2, seg = lane & 3;
        const int grow = tile * 16 + lrow;
        if (grow < M){
            if (STATS){
                const u16* sp = &cstg[wave][lrow][seg * 16];
                uint4 w0 = *(const uint4*)sp;
                uint4 w1 = *(const uint4*)(sp + 8);
                u16* gp = (u16*)outPre + (size_t)grow * N + colbase + seg * 16;
                *(uint4*)gp = w0;
                *(uint4*)(gp + 8) = w1;
            } else {
                const float* sp = (const float*)&cstg[wave][0][0] + lrow * 36 + seg * 8;
                float4 w0 = *(const float4*)sp;
                float4 w1 = *(const float4*)(sp + 4);
                float* gp = (float*)outPre + (size_t)grow * N + colbase + seg * 8;
                *(float4*)gp = w0;
                *(float4*)(gp + 4) = w1;
            }
        }
        asm volatile("" ::: "memory");
    };

    short8 A0[8], A1[8], A2[8];
    int t = blockIdx.x * 2 + (wave >> 1);
    const int stride = nstream;
    if (t < T){
        loadA(A0, t);
        if (t + stride < T) loadA(A1, t + stride);
        while (true){
            int t2 = t + 2 * stride;
            if (t2 < T) loadA(A2, t2);
            compute(A0, t);
            t += stride;
            if (t >= T) break;
            t2 = t + 2 * stride;
            if (t2 < T) loadA(A0, t2);
            compute(A1, t);
            t += stride;
            if (t >= T) break;
            t2 = t + 2 * stride;
            if (t2 < T) loadA(A1, t2);
            compute(A2, t);
            t += stride;
            if (t >= T) break;
        }
    }

    if (STATS){
        #pragma unroll
        for (int nt = 0; nt < NTW; ++nt){
            float s = sS[nt], q = sQ[nt];
            s += __shfl_xor(s, 16);  s += __shfl_xor(s, 32);
            q += __shfl_xor(q, 16);  q += __shfl_xor(q, 32);
            if (lane < 16){
                sbuf[wave][colbase + nt * 16 + m15] = s;
                s2buf[wave][colbase + nt * 16 + m15] = q;
            }
        }
        __syncthreads();
        const int c = threadIdx.x;
        if (c < N){
            float S  = sbuf[0][c] + sbuf[1][c] + sbuf[2][c] + sbuf[3][c];
            float S2 = s2buf[0][c] + s2buf[1][c] + s2buf[2][c] + s2buf[3][c];
            partials[(size_t)blockIdx.x * (2 * N) + c]     = S;
            partials[(size_t)blockIdx.x * (2 * N) + N + c] = S2;
        }
    }
}

// ---------------- BN: reduce block partials; finalize scale/shift ----------------

__global__ __launch_bounds__(256) void bnred_kernel(const float* __restrict__ partials,
                                                    float* __restrict__ cs, int nblk){
    const int t = threadIdx.x;
    float s = 0.f;
    for (int b = blockIdx.x; b < nblk; b += (int)gridDim.x)
        s += partials[(size_t)b * 256 + t];
    atomicAdd(&cs[t], s);
}

__global__ void bnfin_kernel(float* __restrict__ cs, const float* __restrict__ gamma,
                             const float* __restrict__ beta, float invM){
    int c = threadIdx.x;  // 128
    float mu  = cs[c] * invM;
    float var = fmaxf(cs[128 + c] * invM - mu * mu, 0.0f);
    float sc  = gamma[c] * rsqrtf(var + 1e-5f);
    cs[256 + c] = sc;
    cs[384 + c] = beta[c] - mu * sc;
}

// ---------------- log_softmax (one wave per 64-wide row) ----------------

__global__ __launch_bounds__(256) void lsm_kernel(const float* __restrict__ pre,
                                                  float* __restrict__ out, int M){
    const int wave = threadIdx.x >> 6;
    const int lane = threadIdx.x & 63;
    const int row = blockIdx.x * 4 + wave;
    if (row >= M) return;
    float v = pre[(size_t)row * 64 + lane];
    float m = v;
    #pragma unroll
    for (int o = 32; o; o >>= 1) m = fmaxf(m, __shfl_xor(m, o));
    float e = __expf(v - m);
    float s = e;
    #pragma unroll
    for (int o = 32; o; o >>= 1) s += __shfl_xor(s, o);
    out[(size_t)row * 64 + lane] = v - m - __logf(s);
}

// ---------------- host ----------------

extern "C" void kernel_launch(void* const* d_in, const int* in_sizes, int n_in,
                              void* d_out, int out_size, void* d_ws, size_t ws_size,
                              hipStream_t stream) {
    const float* x   = (const float*)d_in[0];
    const int*   src = (const int*)d_in[1];
    const int*   dst = (const int*)d_in[2];
    const float* wself[3]  = {(const float*)d_in[3], (const float*)d_in[6], (const float*)d_in[9]};
    const float* wneigh[3] = {(const float*)d_in[4], (const float*)d_in[7], (const float*)d_in[10]};
    const float* bias[3]   = {(const float*)d_in[5], (const float*)d_in[8], (const float*)d_in[11]};
    const float* gamma[2]  = {(const float*)d_in[12], (const float*)d_in[14]};
    const float* beta[2]   = {(const float*)d_in[13], (const float*)d_in[15]};

    const int M = in_sizes[0] / 128;   // 100000
    const int E = in_sizes[1];         // 1600000
    const int NBUK = (M + 511) / 512;  // 196
    const int T = (M + 15) / 16;
    const int GB = 1024;

    char* ws = (char*)d_ws;
    size_t off = 0;
    auto alloc = [&](size_t bytes) -> void* {
        void* p = ws + off;
        off = (off + bytes + 511) & ~(size_t)511;
        return p;
    };
    int*   gbcnt  = (int*)alloc(256 * 4);
    int*   bbase  = (int*)alloc(256 * 4);
    int*   bcur   = (int*)alloc(256 * 4);
    int*   indptr = (int*)alloc((size_t)(M + 1) * 4);
    u32*   pairs  = (u32*)alloc((size_t)E * 4);
    int*   esrc   = (int*)alloc((size_t)E * 4);
    float* invdeg = (float*)alloc((size_t)M * 4);
    u16* bpack0 = (u16*)alloc(128 * 256 * 2);
    u16* bpack1 = (u16*)alloc(128 * 256 * 2);
    u16* bpack2 = (u16*)alloc(64 * 256 * 2);
    float* colstat0 = (float*)alloc(512 * 4);
    float* colstat1 = (float*)alloc(512 * 4);
    float* partials = (float*)alloc((size_t)GB * 256 * 4);
    u16*   hbuf   = (u16*)alloc((size_t)M * 128 * 2);   // bf16(x)
    u16*   aggbuf = (u16*)alloc((size_t)M * 128 * 2);
    u16*   preA   = (u16*)alloc((size_t)M * 128 * 2);   // layer0 pre-BN (bf16)
    u16*   preB   = (u16*)alloc((size_t)M * 128 * 2);   // layer1 pre-BN (bf16)
    float* preF   = (float*)alloc((size_t)M * 64 * 4);  // final logits (f32)
    u8*    x8     = (u8*)alloc((size_t)M * 128);        // fp8 gather tables (activated for L1/L2)
    u8*    preA8  = (u8*)alloc((size_t)M * 128);
    u8*    preB8  = (u8*)alloc((size_t)M * 128);

    // --- CSR build ---
    hipMemsetAsync(gbcnt, 0, 256 * 4, stream);
    bhist_kernel<<<(E + 8191) / 8192, 256, 0, stream>>>(dst, gbcnt, E);
    bscan_kernel<<<1, 256, 0, stream>>>(gbcnt, bbase, bcur, NBUK);
    bin_kernel<<<(E + BIN_TILE - 1) / BIN_TILE, 256, 0, stream>>>(src, dst, bcur, pairs, E, NBUK);
    sort2_kernel<<<NBUK, 256, 0, stream>>>(pairs, bbase, indptr, invdeg, esrc, M, E, NBUK);

    // --- bf16+fp8 convert + weight pack ---
    cvt_kernel<<<((M * 32) + 255) / 256, 256, 0, stream>>>(x, hbuf, (u32*)x8, M * 32);
    pack_kernel<<<(128 * 256 + 255) / 256, 256, 0, stream>>>(wself[0], wneigh[0], bpack0, 128);
    pack_kernel<<<(128 * 256 + 255) / 256, 256, 0, stream>>>(wself[1], wneigh[1], bpack1, 128);
    pack_kernel<<<(64 * 256 + 255) / 256, 256, 0, stream>>>(wself[2], wneigh[2], bpack2, 64);

    // --- layer 0 ---
    agg_kernel<<<(M + 31) / 32, 256, 0, stream>>>(x8, indptr, esrc, invdeg, aggbuf, M);
    gemm2_kernel<4, true, false><<<GB, 256, 0, stream>>>(hbuf, aggbuf, bpack0, bias[0], nullptr,
                                                         preA, partials, M, T, GB * 2);
    hipMemsetAsync(colstat0, 0, 256 * 4, stream);
    bnred_kernel<<<32, 256, 0, stream>>>(partials, colstat0, GB);
    bnfin_kernel<<<1, 128, 0, stream>>>(colstat0, gamma[0], beta[0], 1.0f / (float)M);
    cvt8a_kernel<<<((M * 16) + 255) / 256, 256, 0, stream>>>(preA, colstat0, (uint2*)preA8, M * 16);

    // --- layer 1 (fp8 table already activated; agg is affine-free) ---
    agg_kernel<<<(M + 31) / 32, 256, 0, stream>>>(preA8, indptr, esrc, invdeg, aggbuf, M);
    gemm2_kernel<4, true, true><<<GB, 256, 0, stream>>>(preA, aggbuf, bpack1, bias[1], colstat0,
                                                        preB, partials, M, T, GB * 2);
    hipMemsetAsync(colstat1, 0, 256 * 4, stream);
    bnred_kernel<<<32, 256, 0, stream>>>(partials, colstat1, GB);
    bnfin_kernel<<<1, 128, 0, stream>>>(colstat1, gamma[1], beta[1], 1.0f / (float)M);
    cvt8a_kernel<<<((M * 16) + 255) / 256, 256, 0, stream>>>(preB, colstat1, (uint2*)preB8, M * 16);

    // --- layer 2 ---
    agg_kernel<<<(M + 31) / 32, 256, 0, stream>>>(preB8, indptr, esrc, invdeg, aggbuf, M);
    gemm2_kernel<2, false, true><<<GB, 256, 0, stream>>>(preB, aggbuf, bpack2, bias[2], colstat1,
                                                         preF, partials, M, T, GB * 2);
    lsm_kernel<<<(M + 3) / 4, 256, 0, stream>>>(preF, (float*)d_out, M);
}

// Round 3
// 427.922 us; speedup vs baseline: 1.1363x; 1.1363x over previous
//
#include <hip/hip_runtime.h>
#include <hip/hip_bf16.h>

typedef unsigned short u16;
typedef unsigned char  u8;
typedef unsigned int   u32;
typedef __attribute__((ext_vector_type(8))) short short8;
typedef __attribute__((ext_vector_type(4))) float floatx4;
typedef __attribute__((ext_vector_type(2))) float floatx2;

__device__ __forceinline__ float bits2f(u32 v){ float f; __builtin_memcpy(&f, &v, 4); return f; }
__device__ __forceinline__ u16 f2bf(float f){
    __hip_bfloat16 h = __float2bfloat16(f);
    u16 u; __builtin_memcpy(&u, &h, 2); return u;
}

// global -> LDS async DMA, 16 B per lane, dest = wave-uniform base + lane*16
__device__ __forceinline__ void gload_lds16(const void* g, void* l){
    __builtin_amdgcn_global_load_lds(
        (const __attribute__((address_space(1))) unsigned char*)g,
        (__attribute__((address_space(3))) unsigned char*)l, 16, 0, 0);
}

// ---------------- f32 -> bf16 + fp8 conversion (x into hbuf, x8) ----------------

__global__ __launch_bounds__(256) void cvt_kernel(const float* __restrict__ in,
                                                  u16* __restrict__ out,
                                                  u32* __restrict__ out8, int total4){
    int i = blockIdx.x * 256 + threadIdx.x;   // 4 floats per thread
    if (i >= total4) return;
    float4 v = ((const float4*)in)[i];
    uint2 o;
    o.x = (u32)f2bf(v.x) | ((u32)f2bf(v.y) << 16);
    o.y = (u32)f2bf(v.z) | ((u32)f2bf(v.w) << 16);
    ((uint2*)out)[i] = o;
    u32 p8 = (u32)__builtin_amdgcn_cvt_pk_fp8_f32(v.x, v.y, 0, false);
    p8     = (u32)__builtin_amdgcn_cvt_pk_fp8_f32(v.z, v.w, (int)p8, true);
    out8[i] = p8;
}

// ------- bf16 pre -> fp8 activated table: fp8(relu(pre*sc + sh)) -------

__global__ __launch_bounds__(256) void cvt8a_kernel(const u16* __restrict__ in,
                                                    const float* __restrict__ cs,
                                                    uint2* __restrict__ out8, int total8){
    int i = blockIdx.x * 256 + threadIdx.x;   // 8 bf16 per thread
    if (i >= total8) return;
    const int c0 = (i & 15) * 8;              // 128 channels per row, 16 threads/row
    uint4 v = ((const uint4*)in)[i];
    u32 w[4] = {v.x, v.y, v.z, v.w};
    float f[8];
    #pragma unroll
    for (int j = 0; j < 4; ++j){
        f[2*j]   = bits2f(w[j] << 16);
        f[2*j+1] = bits2f(w[j] & 0xffff0000u);
    }
    #pragma unroll
    for (int j = 0; j < 8; ++j)
        f[j] = fmaxf(fmaf(f[j], cs[256 + c0 + j], cs[384 + c0 + j]), 0.f);
    u32 lo = (u32)__builtin_amdgcn_cvt_pk_fp8_f32(f[0], f[1], 0, false);
    lo     = (u32)__builtin_amdgcn_cvt_pk_fp8_f32(f[2], f[3], (int)lo, true);
    u32 hi = (u32)__builtin_amdgcn_cvt_pk_fp8_f32(f[4], f[5], 0, false);
    hi     = (u32)__builtin_amdgcn_cvt_pk_fp8_f32(f[6], f[7], (int)hi, true);
    uint2 o; o.x = lo; o.y = hi;
    out8[i] = o;
}

// ---------------- CSR build: bucket hist -> bucket scan -> multisplit bin -> bucket sort ----------------

__global__ __launch_bounds__(256) void bhist_kernel(const int* __restrict__ dst,
                                                    int* __restrict__ gbcnt, int E){
    __shared__ int bc[256];
    const int t = threadIdx.x;
    bc[t] = 0;
    __syncthreads();
    const int tile0 = blockIdx.x * 8192;
    const int cnt = min(8192, E - tile0);
    for (int j = t; j < cnt; j += 256) atomicAdd(&bc[dst[tile0 + j] >> 9], 1);
    __syncthreads();
    if (bc[t] > 0) atomicAdd(&gbcnt[t], bc[t]);
}

__global__ __launch_bounds__(256) void bscan_kernel(const int* __restrict__ gbcnt,
                                                    int* __restrict__ bbase,
                                                    int* __restrict__ bcur, int nbuk){
    __shared__ int ws[4];
    const int t = threadIdx.x, lane = t & 63, wv = t >> 6;
    int v = (t < nbuk) ? gbcnt[t] : 0;
    int s = v;
    for (int off = 1; off < 64; off <<= 1){
        int n = __shfl_up(s, off);
        if (lane >= off) s += n;
    }
    if (lane == 63) ws[wv] = s;
    __syncthreads();
    int woff = 0;
    for (int w = 0; w < wv; ++w) woff += ws[w];
    int excl = s + woff - v;
    if (t < nbuk){ bbase[t] = excl; bcur[t] = excl; }
}

#define BIN_TILE 8192
__global__ __launch_bounds__(256) void bin_kernel(const int* __restrict__ src,
                                                  const int* __restrict__ dst,
                                                  int* __restrict__ bcur,
                                                  u32* __restrict__ pairs, int E, int nbuk){
    __shared__ u32 hcnt[256], hexcl[256], hoff[256];
    __shared__ int gbase[256];
    __shared__ u32 stage[BIN_TILE];
    __shared__ unsigned char bkt[BIN_TILE];
    const int t = threadIdx.x;
    const int tile0 = blockIdx.x * BIN_TILE;
    const int cntE = min(BIN_TILE, E - tile0);

    hcnt[t] = 0;
    __syncthreads();
    for (int j = t; j < cntE; j += 256){
        int d = dst[tile0 + j];
        atomicAdd(&hcnt[d >> 9], 1u);
    }
    __syncthreads();
    if (t < 64){
        u32 a0 = hcnt[4*t], a1 = hcnt[4*t+1], a2 = hcnt[4*t+2], a3 = hcnt[4*t+3];
        u32 lsum = a0 + a1 + a2 + a3;
        u32 s = lsum;
        for (int off = 1; off < 64; off <<= 1){
            u32 n = __shfl_up(s, off);
            if (t >= off) s += n;
        }
        u32 base = s - lsum;
        hexcl[4*t]   = base;
        hexcl[4*t+1] = base + a0;
        hexcl[4*t+2] = base + a0 + a1;
        hexcl[4*t+3] = base + a0 + a1 + a2;
        hoff[4*t]   = base;
        hoff[4*t+1] = base + a0;
        hoff[4*t+2] = base + a0 + a1;
        hoff[4*t+3] = base + a0 + a1 + a2;
    }
    __syncthreads();
    if (t < nbuk && hcnt[t] > 0) gbase[t] = atomicAdd(&bcur[t], (int)hcnt[t]);
    for (int j = t; j < cntE; j += 256){
        int d = dst[tile0 + j];
        int s = src[tile0 + j];
        int b = d >> 9;
        u32 p = atomicAdd(&hoff[b], 1u);
        stage[p] = ((u32)s << 9) | (u32)(d & 511);
        bkt[p] = (unsigned char)b;
    }
    __syncthreads();
    for (int j = t; j < cntE; j += 256){
        int b = bkt[j];
        pairs[gbase[b] + (int)((u32)j - hexcl[b])] = stage[j];
    }
}

__global__ __launch_bounds__(256) void sort2_kernel(const u32* __restrict__ pairs,
                                                    const int* __restrict__ bbase,
                                                    int* __restrict__ indptr,
                                                    float* __restrict__ invdeg,
                                                    int* __restrict__ esrc,
                                                    int M, int E, int nbuk){
    __shared__ int ndeg[512];
    __shared__ int cur[512];
    __shared__ int wsI[4];
    const int b = blockIdx.x;
    const int node0 = b * 512;
    const int lo = bbase[b];
    const int hi = (b + 1 < nbuk) ? bbase[b + 1] : E;
    const int t = threadIdx.x, lane = t & 63, wv = t >> 6;

    ndeg[t] = 0; ndeg[t + 256] = 0;
    __syncthreads();
    for (int i = lo + t; i < hi; i += 256) atomicAdd(&ndeg[pairs[i] & 511], 1);
    __syncthreads();

    const int d0 = ndeg[2*t], d1 = ndeg[2*t + 1];
    const int p = d0 + d1;
    int s = p;
    for (int off = 1; off < 64; off <<= 1){
        int n = __shfl_up(s, off);
        if (lane >= off) s += n;
    }
    if (lane == 63) wsI[wv] = s;
    __syncthreads();
    int woff = 0;
    for (int w = 0; w < wv; ++w) woff += wsI[w];
    const int incl = s + woff;
    const int excl0 = incl - p;
    const int excl1 = excl0 + d0;

    const int n0 = node0 + 2*t, n1 = node0 + 2*t + 1;
    if (n0 < M){
        indptr[n0 + 1] = lo + excl0 + d0;
        invdeg[n0] = 1.0f / (float)max(d0, 1);
        cur[2*t] = lo + excl0;
    }
    if (n1 < M){
        indptr[n1 + 1] = lo + excl1 + d1;
        invdeg[n1] = 1.0f / (float)max(d1, 1);
        cur[2*t + 1] = lo + excl1;
    }
    if (b == 0 && t == 0) indptr[0] = 0;
    __syncthreads();
    for (int i = lo + t; i < hi; i += 256){
        u32 v = pairs[i];
        int pos = atomicAdd(&cur[v & 511], 1);
        esrc[pos] = (int)(v >> 9);
    }
}

// ------- weight packing -------

__global__ void pack_kernel(const float* __restrict__ wself, const float* __restrict__ wneigh,
                            u16* __restrict__ bp, int N){
    int i = blockIdx.x * 256 + threadIdx.x;
    if (i >= N * 256) return;
    int n = i >> 8, k = i & 255;
    float v = (k < 128) ? wself[k * N + n] : wneigh[(k - 128) * N + n];
    bp[i] = f2bf(v);
}

// ---------------- aggregation over fp8 table ----------------
// One 8-lane group per node (8 nodes/wave). Lane l8 owns 16 fp8 channels (16 B).

__global__ __launch_bounds__(256) void agg_kernel(const u8* __restrict__ h8,
                                                  const int* __restrict__ indptr,
                                                  const int* __restrict__ esrc,
                                                  const float* __restrict__ invdeg,
                                                  u16* __restrict__ agg, int M){
    const int l8 = threadIdx.x & 7;
    const int n = (blockIdx.x * 256 + threadIdx.x) >> 3;
    if (n >= M) return;
    const int beg = indptr[n];
    const int end = indptr[n + 1];
    const float fs = invdeg[n];

    floatx2 acc[8];
    #pragma unroll
    for (int i = 0; i < 8; ++i){ acc[i].x = 0.f; acc[i].y = 0.f; }

    const u8* hb = h8 + l8 * 16;

    auto accum = [&](uint4 v){
        u32 w[4] = {v.x, v.y, v.z, v.w};
        #pragma unroll
        for (int j = 0; j < 4; ++j){
            acc[2*j]   += __builtin_amdgcn_cvt_pk_f32_fp8(w[j], false);
            acc[2*j+1] += __builtin_amdgcn_cvt_pk_f32_fp8(w[j], true);
        }
    };

    int e = beg;
    for (; e + 4 <= end; e += 4){
        const int i0 = esrc[e];
        const int i1 = esrc[e + 1];
        const int i2 = esrc[e + 2];
        const int i3 = esrc[e + 3];
        uint4 v0 = *(const uint4*)(hb + (size_t)i0 * 128);
        uint4 v1 = *(const uint4*)(hb + (size_t)i1 * 128);
        uint4 v2 = *(const uint4*)(hb + (size_t)i2 * 128);
        uint4 v3 = *(const uint4*)(hb + (size_t)i3 * 128);
        accum(v0); accum(v1); accum(v2); accum(v3);
    }
    for (; e < end; ++e){
        const int i0 = esrc[e];
        uint4 v0 = *(const uint4*)(hb + (size_t)i0 * 128);
        accum(v0);
    }

    u32 o[8];
    #pragma unroll
    for (int k = 0; k < 8; ++k)
        o[k] = (u32)f2bf(acc[k].x * fs) | ((u32)f2bf(acc[k].y * fs) << 16);
    uint4 w0 = {o[0], o[1], o[2], o[3]};
    uint4 w1 = {o[4], o[5], o[6], o[7]};
    *(uint4*)(agg + (size_t)n * 128 + l8 * 16)     = w0;
    *(uint4*)(agg + (size_t)n * 128 + l8 * 16 + 8) = w1;
}

// ------- GEMM v3: block-cooperative. A tile staged ONCE per block into LDS via
// global_load_lds (k-major layout [k0][quad][row][16B] -> conflict-free b128 reads,
// linear DMA dest). 4 waves split output cols (NTW per wave). B in registers.
// 3-deep LDS ring, counted vmcnt, raw s_barrier (prefetch survives barriers).
// C staged in LDS (double-buffered), stored as full contiguous 4-KB row blocks. -------

template<int NTW, bool STATS, bool AFFA>
__global__ __launch_bounds__(256, 4) void gemm3_kernel(const u16* __restrict__ hA,
                                                       const u16* __restrict__ aggA,
                                                       const u16* __restrict__ Bp,
                                                       const float* __restrict__ bias,
                                                       const float* __restrict__ cs,
                                                       void* __restrict__ outPre,
                                                       float* __restrict__ partials,
                                                       int M, int T, int GBs){
    constexpr int N = NTW * 64;                 // output width (4 waves x NTW x 16)
    __shared__ __align__(16) u16 Abuf[3][4096]; // 3 x 8KB A tiles, [k0][quad][row][8 u16]
    __shared__ __align__(16) char cbuf[2][4352];// C staging (u16 stride 136 / f32 stride 68)
    __shared__ float s_sc[128], s_sh[128];

    const int wave = threadIdx.x >> 6;
    const int lane = threadIdx.x & 63;
    const int m15 = lane & 15;
    const int quad = lane >> 4;
    const int colbase = wave * (NTW * 16);

    if (AFFA && threadIdx.x < 128){
        s_sc[threadIdx.x] = cs[256 + threadIdx.x];
        s_sh[threadIdx.x] = cs[384 + threadIdx.x];
    }
    __syncthreads();   // once, before any prefetch is in flight

    short8 breg[NTW][8];
    float bv[NTW];
    #pragma unroll
    for (int nt = 0; nt < NTW; ++nt){
        bv[nt] = bias[colbase + nt * 16 + m15];
        #pragma unroll
        for (int k0 = 0; k0 < 8; ++k0)
            breg[nt][k0] = *(const short8*)(Bp + (size_t)(colbase + nt * 16 + m15) * 256 + k0 * 32 + quad * 8);
    }

    float sS[NTW], sQ[NTW];
    #pragma unroll
    for (int nt = 0; nt < NTW; ++nt){ sS[nt] = 0.f; sQ[nt] = 0.f; }

    // wave w stages k0 = 2w, 2w+1 (2 x 1KB DMA per wave per tile)
    auto stage = [&](int bufIdx, int tile){
        const int srow = lane & 15, squad = lane >> 4;
        int arow = tile * 16 + srow;
        if (arow >= M) arow = M - 1;
        #pragma unroll
        for (int h = 0; h < 2; ++h){
            const int k0 = wave * 2 + h;
            const u16* base = (k0 < 4) ? hA : aggA;
            const u16* g = base + (size_t)arow * 128 + (k0 & 3) * 32 + squad * 8;
            gload_lds16(g, &Abuf[bufIdx][k0 * 512]);
        }
    };

    const int t0 = blockIdx.x;
    const int nIter = (T - 1 - t0) / GBs + 1;

    stage(0, t0);
    if (nIter > 1) stage(1, t0 + GBs);

    int t = t0;
    for (int it = 0; it < nIter; ++it){
        const int cur = it % 3;
        if (it + 2 < nIter) stage((it + 2) % 3, t + 2 * GBs);

        const int ahead = min(nIter - 1 - it, 2);
        if (ahead >= 2)      asm volatile("s_waitcnt vmcnt(4)" ::: "memory");
        else if (ahead == 1) asm volatile("s_waitcnt vmcnt(2)" ::: "memory");
        else                 asm volatile("s_waitcnt vmcnt(0)" ::: "memory");
        __builtin_amdgcn_s_barrier();
        __builtin_amdgcn_sched_barrier(0);

        floatx4 acc[NTW];
        #pragma unroll
        for (int nt = 0; nt < NTW; ++nt) acc[nt] = 0.0f;
        #pragma unroll
        for (int k0 = 0; k0 < 8; ++k0){
            short8 a = *(const short8*)&Abuf[cur][k0 * 512 + quad * 128 + m15 * 8];
            if (AFFA && k0 < 4){
                const int cb = k0 * 32 + quad * 8;
                #pragma unroll
                for (int j = 0; j < 8; ++j){
                    float f = bits2f(((u32)(u16)a[j]) << 16);
                    f = fmaxf(fmaf(f, s_sc[cb + j], s_sh[cb + j]), 0.f);
                    a[j] = (short)f2bf(f);
                }
            }
            #pragma unroll
            for (int nt = 0; nt < NTW; ++nt)
                acc[nt] = __builtin_amdgcn_mfma_f32_16x16x32_bf16(a, breg[nt][k0], acc[nt], 0, 0, 0);
        }

        // ---- epilogue: bias (+stats), stage C tile in LDS ----
        char* cb = &cbuf[it & 1][0];
        const int r0 = quad * 4;
        #pragma unroll
        for (int nt = 0; nt < NTW; ++nt){
            const int col = colbase + nt * 16 + m15;
            #pragma unroll
            for (int r = 0; r < 4; ++r){
                float v = acc[nt][r] + bv[nt];
                if (STATS){
                    int row = t * 16 + r0 + r;
                    if (row < M){
                        sS[nt] += v;
                        sQ[nt] = fmaf(v, v, sQ[nt]);
                    }
                    ((u16*)cb)[(r0 + r) * 136 + col] = f2bf(v);
                } else {
                    ((float*)cb)[(r0 + r) * 68 + col] = v;
                }
            }
        }
        asm volatile("s_waitcnt lgkmcnt(0)" ::: "memory");
        __builtin_amdgcn_s_barrier();          // C visible; also fences Abuf[cur] reuse
        __builtin_amdgcn_sched_barrier(0);

        const int srow = threadIdx.x >> 4, seg = threadIdx.x & 15;
        const int grow = t * 16 + srow;
        if (grow < M){
            if (STATS){
                uint4 w = *(const uint4*)((const u16*)cb + srow * 136 + seg * 8);
                *(uint4*)((u16*)outPre + (size_t)grow * N + seg * 8) = w;
            } else {
                float4 w = *(const float4*)((const float*)cb + srow * 68 + seg * 4);
                *(float4*)((float*)outPre + (size_t)grow * N + seg * 4) = w;
            }
        }
        t += GBs;
    }

    if (STATS){
        #pragma unroll
        for (int nt = 0; nt < NTW; ++nt){
            float s = sS[nt], q = sQ[nt];
            s += __shfl_xor(s, 16);  s += __shfl_xor(s, 32);
            q += __shfl_xor(q, 16);  q += __shfl_xor(q, 32);
            if (quad == 0){
                const int c = colbase + nt * 16 + m15;
                partials[(size_t)blockIdx.x * 256 + c]       = s;
                partials[(size_t)blockIdx.x * 256 + 128 + c] = q;
            }
        }
    }
}

// ---------------- BN: reduce block partials; finalize scale/shift ----------------

__global__ __launch_bounds__(256) void bnred_kernel(const float* __restrict__ partials,
                                                    float* __restrict__ cs, int nblk){
    const int t = threadIdx.x;
    float s = 0.f;
    for (int b = blockIdx.x; b < nblk; b += (int)gridDim.x)
        s += partials[(size_t)b * 256 + t];
    atomicAdd(&cs[t], s);
}

__global__ void bnfin_kernel(float* __restrict__ cs, const float* __restrict__ gamma,
                             const float* __restrict__ beta, float invM){
    int c = threadIdx.x;  // 128
    float mu  = cs[c] * invM;
    float var = fmaxf(cs[128 + c] * invM - mu * mu, 0.0f);
    float sc  = gamma[c] * rsqrtf(var + 1e-5f);
    cs[256 + c] = sc;
    cs[384 + c] = beta[c] - mu * sc;
}

// ---------------- log_softmax (one wave per 64-wide row) ----------------

__global__ __launch_bounds__(256) void lsm_kernel(const float* __restrict__ pre,
                                                  float* __restrict__ out, int M){
    const int wave = threadIdx.x >> 6;
    const int lane = threadIdx.x & 63;
    const int row = blockIdx.x * 4 + wave;
    if (row >= M) return;
    float v = pre[(size_t)row * 64 + lane];
    float m = v;
    #pragma unroll
    for (int o = 32; o; o >>= 1) m = fmaxf(m, __shfl_xor(m, o));
    float e = __expf(v - m);
    float s = e;
    #pragma unroll
    for (int o = 32; o; o >>= 1) s += __shfl_xor(s, o);
    out[(size_t)row * 64 + lane] = v - m - __logf(s);
}

// ---------------- host ----------------

extern "C" void kernel_launch(void* const* d_in, const int* in_sizes, int n_in,
                              void* d_out, int out_size, void* d_ws, size_t ws_size,
                              hipStream_t stream) {
    const float* x   = (const float*)d_in[0];
    const int*   src = (const int*)d_in[1];
    const int*   dst = (const int*)d_in[2];
    const float* wself[3]  = {(const float*)d_in[3], (const float*)d_in[6], (const float*)d_in[9]};
    const float* wneigh[3] = {(const float*)d_in[4], (const float*)d_in[7], (const float*)d_in[10]};
    const float* bias[3]   = {(const float*)d_in[5], (const float*)d_in[8], (const float*)d_in[11]};
    const float* gamma[2]  = {(const float*)d_in[12], (const float*)d_in[14]};
    const float* beta[2]   = {(const float*)d_in[13], (const float*)d_in[15]};

    const int M = in_sizes[0] / 128;   // 100000
    const int E = in_sizes[1];         // 1600000
    const int NBUK = (M + 511) / 512;  // 196
    const int T = (M + 15) / 16;       // 6250 A-tiles
    const int GB = 1024;               // 4 blocks/CU (LDS ~34 KB, VGPR<=128)

    char* ws = (char*)d_ws;
    size_t off = 0;
    auto alloc = [&](size_t bytes) -> void* {
        void* p = ws + off;
        off = (off + bytes + 511) & ~(size_t)511;
        return p;
    };
    int*   gbcnt  = (int*)alloc(256 * 4);
    int*   bbase  = (int*)alloc(256 * 4);
    int*   bcur   = (int*)alloc(256 * 4);
    int*   indptr = (int*)alloc((size_t)(M + 1) * 4);
    u32*   pairs  = (u32*)alloc((size_t)E * 4);
    int*   esrc   = (int*)alloc((size_t)E * 4);
    float* invdeg = (float*)alloc((size_t)M * 4);
    u16* bpack0 = (u16*)alloc(128 * 256 * 2);
    u16* bpack1 = (u16*)alloc(128 * 256 * 2);
    u16* bpack2 = (u16*)alloc(64 * 256 * 2);
    float* colstat0 = (float*)alloc(512 * 4);
    float* colstat1 = (float*)alloc(512 * 4);
    float* partials = (float*)alloc((size_t)GB * 256 * 4);
    u16*   hbuf   = (u16*)alloc((size_t)M * 128 * 2);   // bf16(x)
    u16*   aggbuf = (u16*)alloc((size_t)M * 128 * 2);
    u16*   preA   = (u16*)alloc((size_t)M * 128 * 2);   // layer0 pre-BN (bf16)
    u16*   preB   = (u16*)alloc((size_t)M * 128 * 2);   // layer1 pre-BN (bf16)
    float* preF   = (float*)alloc((size_t)M * 64 * 4);  // final logits (f32)
    u8*    x8     = (u8*)alloc((size_t)M * 128);        // fp8 gather tables (activated for L1/L2)
    u8*    preA8  = (u8*)alloc((size_t)M * 128);
    u8*    preB8  = (u8*)alloc((size_t)M * 128);

    // --- CSR build ---
    hipMemsetAsync(gbcnt, 0, 256 * 4, stream);
    bhist_kernel<<<(E + 8191) / 8192, 256, 0, stream>>>(dst, gbcnt, E);
    bscan_kernel<<<1, 256, 0, stream>>>(gbcnt, bbase, bcur, NBUK);
    bin_kernel<<<(E + BIN_TILE - 1) / BIN_TILE, 256, 0, stream>>>(src, dst, bcur, pairs, E, NBUK);
    sort2_kernel<<<NBUK, 256, 0, stream>>>(pairs, bbase, indptr, invdeg, esrc, M, E, NBUK);

    // --- bf16+fp8 convert + weight pack ---
    cvt_kernel<<<((M * 32) + 255) / 256, 256, 0, stream>>>(x, hbuf, (u32*)x8, M * 32);
    pack_kernel<<<(128 * 256 + 255) / 256, 256, 0, stream>>>(wself[0], wneigh[0], bpack0, 128);
    pack_kernel<<<(128 * 256 + 255) / 256, 256, 0, stream>>>(wself[1], wneigh[1], bpack1, 128);
    pack_kernel<<<(64 * 256 + 255) / 256, 256, 0, stream>>>(wself[2], wneigh[2], bpack2, 64);

    // --- layer 0 ---
    agg_kernel<<<(M + 31) / 32, 256, 0, stream>>>(x8, indptr, esrc, invdeg, aggbuf, M);
    gemm3_kernel<2, true, false><<<GB, 256, 0, stream>>>(hbuf, aggbuf, bpack0, bias[0], nullptr,
                                                         preA, partials, M, T, GB);
    hipMemsetAsync(colstat0, 0, 256 * 4, stream);
    bnred_kernel<<<32, 256, 0, stream>>>(partials, colstat0, GB);
    bnfin_kernel<<<1, 128, 0, stream>>>(colstat0, gamma[0], beta[0], 1.0f / (float)M);
    cvt8a_kernel<<<((M * 16) + 255) / 256, 256, 0, stream>>>(preA, colstat0, (uint2*)preA8, M * 16);

    // --- layer 1 (fp8 table already activated; agg is affine-free) ---
    agg_kernel<<<(M + 31) / 32, 256, 0, stream>>>(preA8, indptr, esrc, invdeg, aggbuf, M);
    gemm3_kernel<2, true, true><<<GB, 256, 0, stream>>>(preA, aggbuf, bpack1, bias[1], colstat0,
                                                        preB, partials, M, T, GB);
    hipMemsetAsync(colstat1, 0, 256 * 4, stream);
    bnred_kernel<<<32, 256, 0, stream>>>(partials, colstat1, GB);
    bnfin_kernel<<<1, 128, 0, stream>>>(colstat1, gamma[1], beta[1], 1.0f / (float)M);
    cvt8a_kernel<<<((M * 16) + 255) / 256, 256, 0, stream>>>(preB, colstat1, (uint2*)preB8, M * 16);

    // --- layer 2 ---
    agg_kernel<<<(M + 31) / 32, 256, 0, stream>>>(preB8, indptr, esrc, invdeg, aggbuf, M);
    gemm3_kernel<1, false, true><<<GB, 256, 0, stream>>>(preB, aggbuf, bpack2, bias[2], colstat1,
                                                         preF, partials, M, T, GB);
    lsm_kernel<<<(M + 3) / 4, 256, 0, stream>>>(preF, (float*)d_out, M);
}

// Round 4
// 401.958 us; speedup vs baseline: 1.2098x; 1.0646x over previous
//
#include <hip/hip_runtime.h>
#include <hip/hip_bf16.h>

typedef unsigned short u16;
typedef unsigned char  u8;
typedef unsigned int   u32;
typedef __attribute__((ext_vector_type(8))) short short8;
typedef __attribute__((ext_vector_type(4))) float floatx4;
typedef __attribute__((ext_vector_type(2))) float floatx2;

__device__ __forceinline__ float bits2f(u32 v){ float f; __builtin_memcpy(&f, &v, 4); return f; }
__device__ __forceinline__ u16 f2bf(float f){
    __hip_bfloat16 h = __float2bfloat16(f);
    u16 u; __builtin_memcpy(&u, &h, 2); return u;
}

// global -> LDS async DMA, 16 B per lane, dest = wave-uniform base + lane*16
__device__ __forceinline__ void gload_lds16(const void* g, void* l){
    __builtin_amdgcn_global_load_lds(
        (const __attribute__((address_space(1))) unsigned char*)g,
        (__attribute__((address_space(3))) unsigned char*)l, 16, 0, 0);
}

// ---------------- f32 -> bf16 + fp8 conversion (x into hbuf, x8) ----------------

__global__ __launch_bounds__(256) void cvt_kernel(const float* __restrict__ in,
                                                  u16* __restrict__ out,
                                                  u32* __restrict__ out8, int total4){
    int i = blockIdx.x * 256 + threadIdx.x;   // 4 floats per thread
    if (i >= total4) return;
    float4 v = ((const float4*)in)[i];
    uint2 o;
    o.x = (u32)f2bf(v.x) | ((u32)f2bf(v.y) << 16);
    o.y = (u32)f2bf(v.z) | ((u32)f2bf(v.w) << 16);
    ((uint2*)out)[i] = o;
    u32 p8 = (u32)__builtin_amdgcn_cvt_pk_fp8_f32(v.x, v.y, 0, false);
    p8     = (u32)__builtin_amdgcn_cvt_pk_fp8_f32(v.z, v.w, (int)p8, true);
    out8[i] = p8;
}

// ------- bf16 pre -> fp8 activated table: fp8(relu(pre*sc + sh)) -------

__global__ __launch_bounds__(256) void cvt8a_kernel(const u16* __restrict__ in,
                                                    const float* __restrict__ cs,
                                                    uint2* __restrict__ out8, int total8){
    int i = blockIdx.x * 256 + threadIdx.x;   // 8 bf16 per thread
    if (i >= total8) return;
    const int c0 = (i & 15) * 8;              // 128 channels per row, 16 threads/row
    uint4 v = ((const uint4*)in)[i];
    u32 w[4] = {v.x, v.y, v.z, v.w};
    float f[8];
    #pragma unroll
    for (int j = 0; j < 4; ++j){
        f[2*j]   = bits2f(w[j] << 16);
        f[2*j+1] = bits2f(w[j] & 0xffff0000u);
    }
    #pragma unroll
    for (int j = 0; j < 8; ++j)
        f[j] = fmaxf(fmaf(f[j], cs[256 + c0 + j], cs[384 + c0 + j]), 0.f);
    u32 lo = (u32)__builtin_amdgcn_cvt_pk_fp8_f32(f[0], f[1], 0, false);
    lo     = (u32)__builtin_amdgcn_cvt_pk_fp8_f32(f[2], f[3], (int)lo, true);
    u32 hi = (u32)__builtin_amdgcn_cvt_pk_fp8_f32(f[4], f[5], 0, false);
    hi     = (u32)__builtin_amdgcn_cvt_pk_fp8_f32(f[6], f[7], (int)hi, true);
    uint2 o; o.x = lo; o.y = hi;
    out8[i] = o;
}

// ---------------- CSR build: bucket hist -> bucket scan -> multisplit bin -> bucket sort ----------------

__global__ __launch_bounds__(256) void bhist_kernel(const int* __restrict__ dst,
                                                    int* __restrict__ gbcnt, int E){
    __shared__ int bc[256];
    const int t = threadIdx.x;
    bc[t] = 0;
    __syncthreads();
    const int tile0 = blockIdx.x * 8192;
    const int cnt = min(8192, E - tile0);
    for (int j = t; j < cnt; j += 256) atomicAdd(&bc[dst[tile0 + j] >> 9], 1);
    __syncthreads();
    if (bc[t] > 0) atomicAdd(&gbcnt[t], bc[t]);
}

__global__ __launch_bounds__(256) void bscan_kernel(const int* __restrict__ gbcnt,
                                                    int* __restrict__ bbase,
                                                    int* __restrict__ bcur, int nbuk){
    __shared__ int ws[4];
    const int t = threadIdx.x, lane = t & 63, wv = t >> 6;
    int v = (t < nbuk) ? gbcnt[t] : 0;
    int s = v;
    for (int off = 1; off < 64; off <<= 1){
        int n = __shfl_up(s, off);
        if (lane >= off) s += n;
    }
    if (lane == 63) ws[wv] = s;
    __syncthreads();
    int woff = 0;
    for (int w = 0; w < wv; ++w) woff += ws[w];
    int excl = s + woff - v;
    if (t < nbuk){ bbase[t] = excl; bcur[t] = excl; }
}

#define BIN_TILE 8192
__global__ __launch_bounds__(256) void bin_kernel(const int* __restrict__ src,
                                                  const int* __restrict__ dst,
                                                  int* __restrict__ bcur,
                                                  u32* __restrict__ pairs, int E, int nbuk){
    __shared__ u32 hcnt[256], hexcl[256], hoff[256];
    __shared__ int gbase[256];
    __shared__ u32 stage[BIN_TILE];
    __shared__ unsigned char bkt[BIN_TILE];
    const int t = threadIdx.x;
    const int tile0 = blockIdx.x * BIN_TILE;
    const int cntE = min(BIN_TILE, E - tile0);

    hcnt[t] = 0;
    __syncthreads();
    for (int j = t; j < cntE; j += 256){
        int d = dst[tile0 + j];
        atomicAdd(&hcnt[d >> 9], 1u);
    }
    __syncthreads();
    if (t < 64){
        u32 a0 = hcnt[4*t], a1 = hcnt[4*t+1], a2 = hcnt[4*t+2], a3 = hcnt[4*t+3];
        u32 lsum = a0 + a1 + a2 + a3;
        u32 s = lsum;
        for (int off = 1; off < 64; off <<= 1){
            u32 n = __shfl_up(s, off);
            if (t >= off) s += n;
        }
        u32 base = s - lsum;
        hexcl[4*t]   = base;
        hexcl[4*t+1] = base + a0;
        hexcl[4*t+2] = base + a0 + a1;
        hexcl[4*t+3] = base + a0 + a1 + a2;
        hoff[4*t]   = base;
        hoff[4*t+1] = base + a0;
        hoff[4*t+2] = base + a0 + a1;
        hoff[4*t+3] = base + a0 + a1 + a2;
    }
    __syncthreads();
    if (t < nbuk && hcnt[t] > 0) gbase[t] = atomicAdd(&bcur[t], (int)hcnt[t]);
    for (int j = t; j < cntE; j += 256){
        int d = dst[tile0 + j];
        int s = src[tile0 + j];
        int b = d >> 9;
        u32 p = atomicAdd(&hoff[b], 1u);
        stage[p] = ((u32)s << 9) | (u32)(d & 511);
        bkt[p] = (unsigned char)b;
    }
    __syncthreads();
    for (int j = t; j < cntE; j += 256){
        int b = bkt[j];
        pairs[gbase[b] + (int)((u32)j - hexcl[b])] = stage[j];
    }
}

__global__ __launch_bounds__(256) void sort2_kernel(const u32* __restrict__ pairs,
                                                    const int* __restrict__ bbase,
                                                    int* __restrict__ indptr,
                                                    float* __restrict__ invdeg,
                                                    int* __restrict__ esrc,
                                                    int M, int E, int nbuk){
    __shared__ int ndeg[512];
    __shared__ int cur[512];
    __shared__ int wsI[4];
    const int b = blockIdx.x;
    const int node0 = b * 512;
    const int lo = bbase[b];
    const int hi = (b + 1 < nbuk) ? bbase[b + 1] : E;
    const int t = threadIdx.x, lane = t & 63, wv = t >> 6;

    ndeg[t] = 0; ndeg[t + 256] = 0;
    __syncthreads();
    for (int i = lo + t; i < hi; i += 256) atomicAdd(&ndeg[pairs[i] & 511], 1);
    __syncthreads();

    const int d0 = ndeg[2*t], d1 = ndeg[2*t + 1];
    const int p = d0 + d1;
    int s = p;
    for (int off = 1; off < 64; off <<= 1){
        int n = __shfl_up(s, off);
        if (lane >= off) s += n;
    }
    if (lane == 63) wsI[wv] = s;
    __syncthreads();
    int woff = 0;
    for (int w = 0; w < wv; ++w) woff += wsI[w];
    const int incl = s + woff;
    const int excl0 = incl - p;
    const int excl1 = excl0 + d0;

    const int n0 = node0 + 2*t, n1 = node0 + 2*t + 1;
    if (n0 < M){
        indptr[n0 + 1] = lo + excl0 + d0;
        invdeg[n0] = 1.0f / (float)max(d0, 1);
        cur[2*t] = lo + excl0;
    }
    if (n1 < M){
        indptr[n1 + 1] = lo + excl1 + d1;
        invdeg[n1] = 1.0f / (float)max(d1, 1);
        cur[2*t + 1] = lo + excl1;
    }
    if (b == 0 && t == 0) indptr[0] = 0;
    __syncthreads();
    for (int i = lo + t; i < hi; i += 256){
        u32 v = pairs[i];
        int pos = atomicAdd(&cur[v & 511], 1);
        esrc[pos] = (int)(v >> 9);
    }
}

// ------- weight packing: all three layers in one launch -------

__global__ __launch_bounds__(256) void pack3_kernel(const float* __restrict__ w0s, const float* __restrict__ w0n,
                                                    const float* __restrict__ w1s, const float* __restrict__ w1n,
                                                    const float* __restrict__ w2s, const float* __restrict__ w2n,
                                                    u16* __restrict__ bp0, u16* __restrict__ bp1,
                                                    u16* __restrict__ bp2){
    int i = blockIdx.x * 256 + threadIdx.x;   // 81920 total
    const float *ws, *wn; u16* bp; int N;
    if (i < 32768){ ws = w0s; wn = w0n; bp = bp0; N = 128; }
    else if (i < 65536){ i -= 32768; ws = w1s; wn = w1n; bp = bp1; N = 128; }
    else { i -= 65536; ws = w2s; wn = w2n; bp = bp2; N = 64; }
    int n = i >> 8, k = i & 255;
    float v = (k < 128) ? ws[k * N + n] : wn[(k - 128) * N + n];
    bp[i] = f2bf(v);
}

// ---------------- aggregation over fp8 table ----------------
// One 8-lane group per node (8 nodes/wave). Lane l8 owns 16 fp8 channels (16 B).

__global__ __launch_bounds__(256) void agg_kernel(const u8* __restrict__ h8,
                                                  const int* __restrict__ indptr,
                                                  const int* __restrict__ esrc,
                                                  const float* __restrict__ invdeg,
                                                  u16* __restrict__ agg, int M){
    const int l8 = threadIdx.x & 7;
    const int n = (blockIdx.x * 256 + threadIdx.x) >> 3;
    if (n >= M) return;
    const int beg = indptr[n];
    const int end = indptr[n + 1];
    const float fs = invdeg[n];

    floatx2 acc[8];
    #pragma unroll
    for (int i = 0; i < 8; ++i){ acc[i].x = 0.f; acc[i].y = 0.f; }

    const u8* hb = h8 + l8 * 16;

    auto accum = [&](uint4 v){
        u32 w[4] = {v.x, v.y, v.z, v.w};
        #pragma unroll
        for (int j = 0; j < 4; ++j){
            acc[2*j]   += __builtin_amdgcn_cvt_pk_f32_fp8(w[j], false);
            acc[2*j+1] += __builtin_amdgcn_cvt_pk_f32_fp8(w[j], true);
        }
    };

    int e = beg;
    for (; e + 4 <= end; e += 4){
        const int i0 = esrc[e];
        const int i1 = esrc[e + 1];
        const int i2 = esrc[e + 2];
        const int i3 = esrc[e + 3];
        uint4 v0 = *(const uint4*)(hb + (size_t)i0 * 128);
        uint4 v1 = *(const uint4*)(hb + (size_t)i1 * 128);
        uint4 v2 = *(const uint4*)(hb + (size_t)i2 * 128);
        uint4 v3 = *(const uint4*)(hb + (size_t)i3 * 128);
        accum(v0); accum(v1); accum(v2); accum(v3);
    }
    for (; e < end; ++e){
        const int i0 = esrc[e];
        uint4 v0 = *(const uint4*)(hb + (size_t)i0 * 128);
        accum(v0);
    }

    u32 o[8];
    #pragma unroll
    for (int k = 0; k < 8; ++k)
        o[k] = (u32)f2bf(acc[k].x * fs) | ((u32)f2bf(acc[k].y * fs) << 16);
    uint4 w0 = {o[0], o[1], o[2], o[3]};
    uint4 w1 = {o[4], o[5], o[6], o[7]};
    *(uint4*)(agg + (size_t)n * 128 + l8 * 16)     = w0;
    *(uint4*)(agg + (size_t)n * 128 + l8 * 16 + 8) = w1;
}

// ------- GEMM v4: block-cooperative. A tile staged ONCE per block into LDS via
// global_load_lds (k-major [k0][quad][row][16B], linear DMA dest, conflict-free b128).
// 4 waves split output cols. B in registers. 3-deep LDS ring, counted vmcnt,
// raw s_barrier. C staged in LDS, stored as full contiguous row blocks.
// STATS: partials written transposed [channel][block] for the bnstat reducer.
// LSM: log_softmax over the 64-wide row fused into the store phase (layer 2). -------

template<int NTW, bool STATS, bool AFFA, bool LSM>
__global__ __launch_bounds__(256, 4) void gemm3_kernel(const u16* __restrict__ hA,
                                                       const u16* __restrict__ aggA,
                                                       const u16* __restrict__ Bp,
                                                       const float* __restrict__ bias,
                                                       const float* __restrict__ cs,
                                                       void* __restrict__ outPre,
                                                       float* __restrict__ partials,
                                                       int M, int T, int GBs){
    constexpr int N = NTW * 64;                 // output width (4 waves x NTW x 16)
    __shared__ __align__(16) u16 Abuf[3][4096]; // 3 x 8KB A tiles, [k0][quad][row][8 u16]
    __shared__ __align__(16) char cbuf[2][4352];// C staging (u16 stride 136 / f32 stride 68)
    __shared__ float s_sc[128], s_sh[128];

    const int wave = threadIdx.x >> 6;
    const int lane = threadIdx.x & 63;
    const int m15 = lane & 15;
    const int quad = lane >> 4;
    const int colbase = wave * (NTW * 16);

    if (AFFA && threadIdx.x < 128){
        s_sc[threadIdx.x] = cs[256 + threadIdx.x];
        s_sh[threadIdx.x] = cs[384 + threadIdx.x];
    }
    __syncthreads();   // once, before any prefetch is in flight

    short8 breg[NTW][8];
    float bv[NTW];
    #pragma unroll
    for (int nt = 0; nt < NTW; ++nt){
        bv[nt] = bias[colbase + nt * 16 + m15];
        #pragma unroll
        for (int k0 = 0; k0 < 8; ++k0)
            breg[nt][k0] = *(const short8*)(Bp + (size_t)(colbase + nt * 16 + m15) * 256 + k0 * 32 + quad * 8);
    }

    float sS[NTW], sQ[NTW];
    #pragma unroll
    for (int nt = 0; nt < NTW; ++nt){ sS[nt] = 0.f; sQ[nt] = 0.f; }

    // wave w stages k0 = 2w, 2w+1 (2 x 1KB DMA per wave per tile)
    auto stage = [&](int bufIdx, int tile){
        const int srow = lane & 15, squad = lane >> 4;
        int arow = tile * 16 + srow;
        if (arow >= M) arow = M - 1;
        #pragma unroll
        for (int h = 0; h < 2; ++h){
            const int k0 = wave * 2 + h;
            const u16* base = (k0 < 4) ? hA : aggA;
            const u16* g = base + (size_t)arow * 128 + (k0 & 3) * 32 + squad * 8;
            gload_lds16(g, &Abuf[bufIdx][k0 * 512]);
        }
    };

    const int t0 = blockIdx.x;
    const int nIter = (T - 1 - t0) / GBs + 1;

    stage(0, t0);
    if (nIter > 1) stage(1, t0 + GBs);

    int t = t0;
    for (int it = 0; it < nIter; ++it){
        const int cur = it % 3;
        if (it + 2 < nIter) stage((it + 2) % 3, t + 2 * GBs);

        const int ahead = min(nIter - 1 - it, 2);
        if (ahead >= 2)      asm volatile("s_waitcnt vmcnt(4)" ::: "memory");
        else if (ahead == 1) asm volatile("s_waitcnt vmcnt(2)" ::: "memory");
        else                 asm volatile("s_waitcnt vmcnt(0)" ::: "memory");
        __builtin_amdgcn_s_barrier();
        __builtin_amdgcn_sched_barrier(0);

        floatx4 acc[NTW];
        #pragma unroll
        for (int nt = 0; nt < NTW; ++nt) acc[nt] = 0.0f;
        #pragma unroll
        for (int k0 = 0; k0 < 8; ++k0){
            short8 a = *(const short8*)&Abuf[cur][k0 * 512 + quad * 128 + m15 * 8];
            if (AFFA && k0 < 4){
                const int cb = k0 * 32 + quad * 8;
                #pragma unroll
                for (int j = 0; j < 8; ++j){
                    float f = bits2f(((u32)(u16)a[j]) << 16);
                    f = fmaxf(fmaf(f, s_sc[cb + j], s_sh[cb + j]), 0.f);
                    a[j] = (short)f2bf(f);
                }
            }
            #pragma unroll
            for (int nt = 0; nt < NTW; ++nt)
                acc[nt] = __builtin_amdgcn_mfma_f32_16x16x32_bf16(a, breg[nt][k0], acc[nt], 0, 0, 0);
        }

        // ---- epilogue: bias (+stats), stage C tile in LDS ----
        char* cb = &cbuf[it & 1][0];
        const int r0 = quad * 4;
        #pragma unroll
        for (int nt = 0; nt < NTW; ++nt){
            const int col = colbase + nt * 16 + m15;
            #pragma unroll
            for (int r = 0; r < 4; ++r){
                float v = acc[nt][r] + bv[nt];
                if (STATS){
                    int row = t * 16 + r0 + r;
                    if (row < M){
                        sS[nt] += v;
                        sQ[nt] = fmaf(v, v, sQ[nt]);
                    }
                    ((u16*)cb)[(r0 + r) * 136 + col] = f2bf(v);
                } else {
                    ((float*)cb)[(r0 + r) * 68 + col] = v;
                }
            }
        }
        asm volatile("s_waitcnt lgkmcnt(0)" ::: "memory");
        __builtin_amdgcn_s_barrier();          // C visible; also fences Abuf[cur] reuse
        __builtin_amdgcn_sched_barrier(0);

        const int srow = threadIdx.x >> 4, seg = threadIdx.x & 15;
        const int grow = t * 16 + srow;
        if (LSM){
            // full 64-wide row is held by the 16 threads seg=0..15 of this srow
            float4 w = *(const float4*)((const float*)cb + srow * 68 + seg * 4);
            float m = fmaxf(fmaxf(w.x, w.y), fmaxf(w.z, w.w));
            m = fmaxf(m, __shfl_xor(m, 1));
            m = fmaxf(m, __shfl_xor(m, 2));
            m = fmaxf(m, __shfl_xor(m, 4));
            m = fmaxf(m, __shfl_xor(m, 8));
            float e = __expf(w.x - m) + __expf(w.y - m) + __expf(w.z - m) + __expf(w.w - m);
            e += __shfl_xor(e, 1);
            e += __shfl_xor(e, 2);
            e += __shfl_xor(e, 4);
            e += __shfl_xor(e, 8);
            float lg = m + __logf(e);
            if (grow < M){
                float4 o;
                o.x = w.x - lg; o.y = w.y - lg; o.z = w.z - lg; o.w = w.w - lg;
                *(float4*)((float*)outPre + (size_t)grow * 64 + seg * 4) = o;
            }
        } else if (grow < M){
            if (STATS){
                uint4 w = *(const uint4*)((const u16*)cb + srow * 136 + seg * 8);
                *(uint4*)((u16*)outPre + (size_t)grow * N + seg * 8) = w;
            } else {
                float4 w = *(const float4*)((const float*)cb + srow * 68 + seg * 4);
                *(float4*)((float*)outPre + (size_t)grow * N + seg * 4) = w;
            }
        }
        t += GBs;
    }

    if (STATS){
        #pragma unroll
        for (int nt = 0; nt < NTW; ++nt){
            float s = sS[nt], q = sQ[nt];
            s += __shfl_xor(s, 16);  s += __shfl_xor(s, 32);
            q += __shfl_xor(q, 16);  q += __shfl_xor(q, 32);
            if (quad == 0){
                const int c = colbase + nt * 16 + m15;
                partials[(size_t)c * GBs + blockIdx.x]         = s;
                partials[(size_t)(128 + c) * GBs + blockIdx.x] = q;
            }
        }
    }
}

// ---------------- BN: transposed-partials reduce + finalize, one kernel ----------------
// partials layout: [channel 0..127 = sum, 128..255 = sumsq][block 0..GB-1].
// 32 blocks x 4 waves; wave handles one channel (contiguous 4-KB rows).

__global__ __launch_bounds__(256) void bnstat_kernel(const float* __restrict__ partials,
                                                     float* __restrict__ cs,
                                                     const float* __restrict__ gamma,
                                                     const float* __restrict__ beta,
                                                     float invM, int GB){
    const int wv = threadIdx.x >> 6, lane = threadIdx.x & 63;
    const int c = blockIdx.x * 4 + wv;   // 0..127
    float s = 0.f, q = 0.f;
    const float* ps = partials + (size_t)c * GB;
    const float* pq = partials + (size_t)(128 + c) * GB;
    for (int k = lane; k < GB; k += 64){ s += ps[k]; q += pq[k]; }
    #pragma unroll
    for (int o = 32; o; o >>= 1){ s += __shfl_xor(s, o); q += __shfl_xor(q, o); }
    if (lane == 0){
        float mu  = s * invM;
        float var = fmaxf(q * invM - mu * mu, 0.f);
        float sc  = gamma[c] * rsqrtf(var + 1e-5f);
        cs[256 + c] = sc;
        cs[384 + c] = beta[c] - mu * sc;
    }
}

// ---------------- host ----------------

extern "C" void kernel_launch(void* const* d_in, const int* in_sizes, int n_in,
                              void* d_out, int out_size, void* d_ws, size_t ws_size,
                              hipStream_t stream) {
    const float* x   = (const float*)d_in[0];
    const int*   src = (const int*)d_in[1];
    const int*   dst = (const int*)d_in[2];
    const float* wself[3]  = {(const float*)d_in[3], (const float*)d_in[6], (const float*)d_in[9]};
    const float* wneigh[3] = {(const float*)d_in[4], (const float*)d_in[7], (const float*)d_in[10]};
    const float* bias[3]   = {(const float*)d_in[5], (const float*)d_in[8], (const float*)d_in[11]};
    const float* gamma[2]  = {(const float*)d_in[12], (const float*)d_in[14]};
    const float* beta[2]   = {(const float*)d_in[13], (const float*)d_in[15]};

    const int M = in_sizes[0] / 128;   // 100000
    const int E = in_sizes[1];         // 1600000
    const int NBUK = (M + 511) / 512;  // 196
    const int T = (M + 15) / 16;       // 6250 A-tiles
    const int GB = 1024;               // 4 blocks/CU (LDS ~34 KB, VGPR<=128)

    char* ws = (char*)d_ws;
    size_t off = 0;
    auto alloc = [&](size_t bytes) -> void* {
        void* p = ws + off;
        off = (off + bytes + 511) & ~(size_t)511;
        return p;
    };
    int*   gbcnt  = (int*)alloc(256 * 4);
    int*   bbase  = (int*)alloc(256 * 4);
    int*   bcur   = (int*)alloc(256 * 4);
    int*   indptr = (int*)alloc((size_t)(M + 1) * 4);
    u32*   pairs  = (u32*)alloc((size_t)E * 4);
    int*   esrc   = (int*)alloc((size_t)E * 4);
    float* invdeg = (float*)alloc((size_t)M * 4);
    u16* bpack0 = (u16*)alloc(128 * 256 * 2);
    u16* bpack1 = (u16*)alloc(128 * 256 * 2);
    u16* bpack2 = (u16*)alloc(64 * 256 * 2);
    float* colstat0 = (float*)alloc(512 * 4);
    float* colstat1 = (float*)alloc(512 * 4);
    float* partials = (float*)alloc((size_t)GB * 256 * 4);
    u16*   hbuf   = (u16*)alloc((size_t)M * 128 * 2);   // bf16(x)
    u16*   aggbuf = (u16*)alloc((size_t)M * 128 * 2);
    u16*   preA   = (u16*)alloc((size_t)M * 128 * 2);   // layer0 pre-BN (bf16)
    u16*   preB   = (u16*)alloc((size_t)M * 128 * 2);   // layer1 pre-BN (bf16)
    u8*    x8     = (u8*)alloc((size_t)M * 128);        // fp8 gather tables (activated for L1/L2)
    u8*    preA8  = (u8*)alloc((size_t)M * 128);
    u8*    preB8  = (u8*)alloc((size_t)M * 128);

    // --- CSR build ---
    hipMemsetAsync(gbcnt, 0, 256 * 4, stream);
    bhist_kernel<<<(E + 8191) / 8192, 256, 0, stream>>>(dst, gbcnt, E);
    bscan_kernel<<<1, 256, 0, stream>>>(gbcnt, bbase, bcur, NBUK);
    bin_kernel<<<(E + BIN_TILE - 1) / BIN_TILE, 256, 0, stream>>>(src, dst, bcur, pairs, E, NBUK);
    sort2_kernel<<<NBUK, 256, 0, stream>>>(pairs, bbase, indptr, invdeg, esrc, M, E, NBUK);

    // --- bf16+fp8 convert + weight pack ---
    cvt_kernel<<<((M * 32) + 255) / 256, 256, 0, stream>>>(x, hbuf, (u32*)x8, M * 32);
    pack3_kernel<<<320, 256, 0, stream>>>(wself[0], wneigh[0], wself[1], wneigh[1],
                                          wself[2], wneigh[2], bpack0, bpack1, bpack2);

    // --- layer 0 ---
    agg_kernel<<<(M + 31) / 32, 256, 0, stream>>>(x8, indptr, esrc, invdeg, aggbuf, M);
    gemm3_kernel<2, true, false, false><<<GB, 256, 0, stream>>>(hbuf, aggbuf, bpack0, bias[0], nullptr,
                                                                preA, partials, M, T, GB);
    bnstat_kernel<<<32, 256, 0, stream>>>(partials, colstat0, gamma[0], beta[0], 1.0f / (float)M, GB);
    cvt8a_kernel<<<((M * 16) + 255) / 256, 256, 0, stream>>>(preA, colstat0, (uint2*)preA8, M * 16);

    // --- layer 1 (fp8 table already activated; agg is affine-free) ---
    agg_kernel<<<(M + 31) / 32, 256, 0, stream>>>(preA8, indptr, esrc, invdeg, aggbuf, M);
    gemm3_kernel<2, true, true, false><<<GB, 256, 0, stream>>>(preA, aggbuf, bpack1, bias[1], colstat0,
                                                               preB, partials, M, T, GB);
    bnstat_kernel<<<32, 256, 0, stream>>>(partials, colstat1, gamma[1], beta[1], 1.0f / (float)M, GB);
    cvt8a_kernel<<<((M * 16) + 255) / 256, 256, 0, stream>>>(preB, colstat1, (uint2*)preB8, M * 16);

    // --- layer 2 (log_softmax fused into gemm epilogue) ---
    agg_kernel<<<(M + 31) / 32, 256, 0, stream>>>(preB8, indptr, esrc, invdeg, aggbuf, M);
    gemm3_kernel<1, false, true, true><<<GB, 256, 0, stream>>>(preB, aggbuf, bpack2, bias[2], colstat1,
                                                               d_out, partials, M, T, GB);
}